// Round 7
// baseline (102.995 us; speedup 1.0000x reference)
//
#include <hip/hip_runtime.h>

// GAPooling: out[b,n,c] = mean_k x[b, idx[b,n,k], c]
// B=16, N=4096, K=32, C=64, fp32. idx int64-or-int32 (runtime-detected).
//
// R7: dual-pipe via WAVE SPECIALIZATION (R6 redone; m114: separate waves on
// one CU co-schedule on different pipes).
//   Block = 512 thr = 8 waves; grid = 16 b x 16 chunk x 2 half = 512 blocks.
//   All waves stage tile[n]=x[b][n][c0:c0+4] (64 KiB), barrier, then:
//     waves 0..5: LDS points [0,2304): 4-ch chunk gather, ds_read_b128
//                 (pure R5 loop, one pipe, low VGPR).
//     waves 6..7: L2 points [2304,4096): full 256B rows, c=lane, idx rows
//                 readfirstlane-scalarized -> s_load; 32 coalesced row loads
//                 in flight per point (pure R2 loop).
//   Split 2304/1792 matches measured pipe rates (~29us vs ~35us full-size).
//   XCD swizzle: bid%16=b -> bid%8=b%8 keeps x[b]/idx16[b] on one XCD's L2.

#define BB 16
#define NN 4096
#define KK 32
#define CC 64
#define CCH 4
#define NCHUNK (CC / CCH)            // 16
#define THREADS 512
#define PS 2304                      // points via LDS pipe
#define PHALF_PTS (PS / 2)           // 1152 per block
#define LDSW 6                       // LDS waves per block
#define PTS_PER_LDSW (PHALF_PTS / LDSW)   // 192 = 3 x 64
#define L2PTS (NN - PS)              // 1792
#define L2_PER_BLOCK (L2PTS / 32)    // 56
#define L2_PER_WAVE (L2_PER_BLOCK / 2)    // 28

// idx values < 4096: if idx is int64 (little-endian), all odd words are 0.
__device__ __forceinline__ int detect_is64(const int* __restrict__ w) {
    int v = w[2 * (threadIdx.x & 63) + 1];
    return (__ballot(v != 0) == 0ULL) ? 1 : 0;
}

__global__ __launch_bounds__(256)
void pack_idx_kernel(const int* __restrict__ idx32,
                     ushort* __restrict__ out16) {
    const int is64 = detect_is64(idx32);
    const int tid = blockIdx.x * blockDim.x + threadIdx.x;
    const int stride = gridDim.x * blockDim.x;
    const int M = BB * NN * KK;
    if (is64) {
        const int4* __restrict__ in = (const int4*)idx32;
        uint* __restrict__ o = (uint*)out16;
        for (int i = tid; i < M / 2; i += stride) {
            int4 v = in[i];
            o[i] = (uint)(v.x & 0xFFFF) | ((uint)(v.z & 0xFFFF) << 16);
        }
    } else {
        const int4* __restrict__ in = (const int4*)idx32;
        uint2* __restrict__ o = (uint2*)out16;
        for (int i = tid; i < M / 4; i += stride) {
            int4 v = in[i];
            o[i] = make_uint2((uint)(v.x & 0xFFFF) | ((uint)(v.y & 0xFFFF) << 16),
                              (uint)(v.z & 0xFFFF) | ((uint)(v.w & 0xFFFF) << 16));
        }
    }
}

__global__ __launch_bounds__(THREADS, 4)
void gapool_ws_kernel(const float* __restrict__ x,
                      const ushort* __restrict__ idx16,
                      float* __restrict__ out) {
    __shared__ float4 tile[NN];          // 64 KiB: x[b][n][c0:c0+4]

    const int bid = blockIdx.x;          // g*16 + b
    const int b = bid & 15;
    const int g = bid >> 4;              // 0..31 = (half<<4) | chunk
    const int chunk = g & (NCHUNK - 1);
    const int half = g >> 4;
    const int c0 = chunk * CCH;
    const int tid = threadIdx.x;
    const int wv = tid >> 6;
    const int lane = tid & 63;
    const float s = 1.0f / KK;

    const float* __restrict__ xb = x + (size_t)b * NN * CC;
    float* __restrict__ outb = out + (size_t)b * NN * CC;
    const ushort* __restrict__ idxb = idx16 + (size_t)b * NN * KK;

    // ---- stage tile (all waves) ----
    const float4* __restrict__ xb4 = (const float4*)(xb + c0);
    for (int r = tid; r < NN; r += THREADS) {
        tile[r] = xb4[(size_t)r * (CC / 4)];
    }
    __syncthreads();

    if (wv < LDSW) {
        // ---- LDS pipe: 192 points per wave, lane = point ----
        const int p0 = half * PHALF_PTS + wv * PTS_PER_LDSW;
#pragma unroll
        for (int it = 0; it < PTS_PER_LDSW / 64; ++it) {
            const int n = p0 + it * 64 + lane;
            const uint4* __restrict__ ip =
                (const uint4*)(idxb + (size_t)n * KK);
            const uint4 u0 = ip[0], u1 = ip[1], u2 = ip[2], u3 = ip[3];
            const uint w[16] = {u0.x, u0.y, u0.z, u0.w, u1.x, u1.y, u1.z, u1.w,
                                u2.x, u2.y, u2.z, u2.w, u3.x, u3.y, u3.z, u3.w};

            float4 acc0 = make_float4(0.f, 0.f, 0.f, 0.f);
            float4 acc1 = make_float4(0.f, 0.f, 0.f, 0.f);
#pragma unroll
            for (int i = 0; i < 16; ++i) {
                {
                    const float4 v = tile[w[i] & 0xFFFFu];
                    acc0.x += v.x; acc0.y += v.y; acc0.z += v.z; acc0.w += v.w;
                }
                {
                    const float4 v = tile[w[i] >> 16];
                    acc1.x += v.x; acc1.y += v.y; acc1.z += v.z; acc1.w += v.w;
                }
            }
            const float4 r = make_float4((acc0.x + acc1.x) * s,
                                         (acc0.y + acc1.y) * s,
                                         (acc0.z + acc1.z) * s,
                                         (acc0.w + acc1.w) * s);
            *(float4*)(outb + (size_t)n * CC + c0) = r;
        }
    } else {
        // ---- L2 pipe: 28 full-row points per wave, c = lane ----
        const int base = __builtin_amdgcn_readfirstlane(
            PS + g * L2_PER_BLOCK + (wv - LDSW) * L2_PER_WAVE);
        for (int t = 0; t < L2_PER_WAVE; ++t) {
            const int n = base + t;                       // scalar
            const uint* __restrict__ ip =
                (const uint*)(idxb + (size_t)n * KK);     // scalar addr -> s_load
            float acc = 0.f;
#pragma unroll
            for (int i = 0; i < 16; ++i) {
                const uint w = ip[i];
                acc += xb[((w & 0xFFFFu) << 6) + lane];
                acc += xb[((w >> 16) << 6) + lane];
            }
            outb[(size_t)n * CC + lane] = acc * s;
        }
    }
}

extern "C" void kernel_launch(void* const* d_in, const int* in_sizes, int n_in,
                              void* d_out, int out_size, void* d_ws, size_t ws_size,
                              hipStream_t stream) {
    const float* x     = (const float*)d_in[0];
    const int*   idx32 = (const int*)d_in[1];
    float*       out   = (float*)d_out;
    ushort*      idx16 = (ushort*)d_ws;     // 4 MiB of scratch

    pack_idx_kernel<<<1024, 256, 0, stream>>>(idx32, idx16);

    gapool_ws_kernel<<<BB * NCHUNK * 2, THREADS, 0, stream>>>(x, idx16, out);
}

// Round 8
// 89.341 us; speedup vs baseline: 1.1528x; 1.1528x over previous
//
#include <hip/hip_runtime.h>

// GAPooling: out[b,n,c] = mean_k x[b, idx[b,n,k], c]
// B=16, N=4096, K=32, C=64, fp32. idx int64-or-int32 (runtime-detected).
//
// R8: byte-reduction of the R5 LDS-gather structure.
//   prep kernel (one launch): idx -> u16 (4 MiB) AND x -> bf16 chunk-planar
//     xbf[(b*8+chunk)*4096 + n] = uint4 of channels chunk*8..chunk*8+7.
//   main kernel: grid = 16 b x 8 chunk x 4 quarter = 512 blocks (2/CU).
//     tile = contiguous coalesced 64 KiB copy of xbf slice (vs R5's 256 MiB
//     aggregate of strided 16B-of-128B-line fetches). Gather: 1 ds_read_b128
//     per neighbor now covers 8 channels (bf16) -> LDS instrs/CU halved
//     (1024), LDS bytes halved (256 MiB total). Unpack bf16->fp32 exact via
//     <<16 / &0xffff0000; fp32 accumulation.
//   XCD swizzle: bid%16 = b -> bid%8 = b%8.

#define BB 16
#define NN 4096
#define KK 32
#define CC 64
#define CH8 8
#define NCHUNK (CC / CH8)            // 8
#define NQ 4                         // point quarters
#define PTS (NN / NQ)                // 1024
#define THREADS 512
#define IDX16_ELEMS (BB * NN * KK)   // 2M u16 = 4 MiB

__device__ __forceinline__ uint pk_bf16(float a, float b) {
    uint ua = __float_as_uint(a);
    ua = (ua + 0x7fffu + ((ua >> 16) & 1u)) >> 16;
    uint ub = __float_as_uint(b);
    ub = (ub + 0x7fffu + ((ub >> 16) & 1u)) & 0xffff0000u;
    return ua | ub;
}

// Phase A: idx (int64-or-int32) -> packed u16.
// Phase B: x fp32 [b][n][64] -> bf16 chunk-planar uint4 rows.
__global__ __launch_bounds__(256)
void prep_kernel(const float* __restrict__ x,
                 const int* __restrict__ idx32,
                 ushort* __restrict__ idx16,
                 uint4* __restrict__ xbf) {
    int vprobe = idx32[2 * (threadIdx.x & 63) + 1];
    const int is64 = (__ballot(vprobe != 0) == 0ULL) ? 1 : 0;

    const int tid = blockIdx.x * blockDim.x + threadIdx.x;
    const int stride = gridDim.x * blockDim.x;

    if (is64) {
        const int4* __restrict__ in = (const int4*)idx32;   // 2 int64 / int4
        uint* __restrict__ o = (uint*)idx16;
        for (int i = tid; i < IDX16_ELEMS / 2; i += stride) {
            int4 v = in[i];
            o[i] = (uint)(v.x & 0xFFFF) | ((uint)(v.z & 0xFFFF) << 16);
        }
    } else {
        const int4* __restrict__ in = (const int4*)idx32;   // 4 int32 / int4
        uint2* __restrict__ o = (uint2*)idx16;
        for (int i = tid; i < IDX16_ELEMS / 4; i += stride) {
            int4 v = in[i];
            o[i] = make_uint2((uint)(v.x & 0xFFFF) | ((uint)(v.y & 0xFFFF) << 16),
                              (uint)(v.z & 0xFFFF) | ((uint)(v.w & 0xFFFF) << 16));
        }
    }

    const float4* __restrict__ x4 = (const float4*)x;
    for (int row = tid; row < BB * NN; row += stride) {
        const size_t base = (size_t)row * (CC / 4);   // in float4 units
        const int b = row >> 12;
        const int n = row & (NN - 1);
#pragma unroll
        for (int ch = 0; ch < NCHUNK; ++ch) {
            const float4 v0 = x4[base + ch * 2];
            const float4 v1 = x4[base + ch * 2 + 1];
            xbf[(size_t)(b * NCHUNK + ch) * NN + n] =
                make_uint4(pk_bf16(v0.x, v0.y), pk_bf16(v0.z, v0.w),
                           pk_bf16(v1.x, v1.y), pk_bf16(v1.z, v1.w));
        }
    }
}

__device__ __forceinline__ void acc8(float a[8], uint4 r) {
    a[0] += __uint_as_float(r.x << 16);
    a[1] += __uint_as_float(r.x & 0xffff0000u);
    a[2] += __uint_as_float(r.y << 16);
    a[3] += __uint_as_float(r.y & 0xffff0000u);
    a[4] += __uint_as_float(r.z << 16);
    a[5] += __uint_as_float(r.z & 0xffff0000u);
    a[6] += __uint_as_float(r.w << 16);
    a[7] += __uint_as_float(r.w & 0xffff0000u);
}

__global__ __launch_bounds__(THREADS, 4)
void gapool_bf16_kernel(const ushort* __restrict__ idx16,
                        const uint4* __restrict__ xbf,
                        float* __restrict__ out) {
    __shared__ uint4 tile[NN];           // 64 KiB: row n = 8 bf16 channels

    const int bid = blockIdx.x;          // g*16 + b
    const int b = bid & 15;
    const int g = bid >> 4;              // 0..31 = q*8 + chunk
    const int chunk = g & (NCHUNK - 1);
    const int q = g >> 3;
    const int tid = threadIdx.x;
    const float s = 1.0f / KK;

    const ushort* __restrict__ idxq =
        idx16 + ((size_t)b * NN + (size_t)q * PTS) * KK;
    float* __restrict__ outq =
        out + ((size_t)b * NN + (size_t)q * PTS) * CC + chunk * CH8;
    const uint4* __restrict__ src = xbf + (size_t)(b * NCHUNK + chunk) * NN;

    // Preload iter-0 indices (independent of tile; hides behind staging).
    const uint4* __restrict__ ip0 = (const uint4*)(idxq + (size_t)tid * KK);
    uint4 pa = ip0[0], pb = ip0[1], pc = ip0[2], pd = ip0[3];

    // Stage tile: contiguous, fully coalesced 64 KiB copy.
    for (int r = tid; r < NN; r += THREADS) tile[r] = src[r];
    __syncthreads();

    for (int p = tid; p < PTS; p += THREADS) {
        const uint w[16] = {pa.x, pa.y, pa.z, pa.w, pb.x, pb.y, pb.z, pb.w,
                            pc.x, pc.y, pc.z, pc.w, pd.x, pd.y, pd.z, pd.w};
        if (p + THREADS < PTS) {         // prefetch next iteration's idx
            const uint4* ipn =
                (const uint4*)(idxq + (size_t)(p + THREADS) * KK);
            pa = ipn[0]; pb = ipn[1]; pc = ipn[2]; pd = ipn[3];
        }

        float a[8] = {0.f, 0.f, 0.f, 0.f, 0.f, 0.f, 0.f, 0.f};
#pragma unroll
        for (int i = 0; i < 16; ++i) {
            acc8(a, tile[w[i] & 0xFFFFu]);
            acc8(a, tile[w[i] >> 16]);
        }

        float4* op = (float4*)(outq + (size_t)p * CC);
        op[0] = make_float4(a[0] * s, a[1] * s, a[2] * s, a[3] * s);
        op[1] = make_float4(a[4] * s, a[5] * s, a[6] * s, a[7] * s);
    }
}

extern "C" void kernel_launch(void* const* d_in, const int* in_sizes, int n_in,
                              void* d_out, int out_size, void* d_ws, size_t ws_size,
                              hipStream_t stream) {
    const float* x     = (const float*)d_in[0];
    const int*   idx32 = (const int*)d_in[1];
    float*       out   = (float*)d_out;
    ushort*      idx16 = (ushort*)d_ws;                       // 4 MiB
    uint4*       xbf   = (uint4*)((char*)d_ws + IDX16_ELEMS * 2);  // 8 MiB

    prep_kernel<<<256, 256, 0, stream>>>(x, idx32, idx16, xbf);

    gapool_bf16_kernel<<<BB * NCHUNK * NQ, THREADS, 0, stream>>>(
        idx16, xbf, out);
}